// Round 17
// baseline (120.471 us; speedup 1.0000x reference)
//
#include <hip/hip_runtime.h>
#include <math.h>

#define NPOS 65536          // D*H*W = 16*64*64
#define DD 16
#define HHH 64
#define WWW 64
#define K3CHUNK 64

typedef __attribute__((ext_vector_type(8))) _Float16 h16x8;  // 8 f16 (4 VGPR)
typedef __attribute__((ext_vector_type(4))) short s16x4;
typedef __attribute__((ext_vector_type(4))) float f32x4;
typedef __attribute__((ext_vector_type(2))) _Float16 f16x2;

static __device__ __forceinline__ short f2h(float f) {
    union { _Float16 h; short s; } v; v.h = (_Float16)f; return v.s;
}
static __device__ __forceinline__ f16x2 i2h(int i) {
    union { int i; f16x2 h; } v; v.i = i; return v.h;
}
static __device__ __forceinline__ int h2i(f16x2 h) {
    union { int i; f16x2 h; } v; v.h = h; return v.i;
}
static __device__ __forceinline__ float fdot2f(f16x2 a, f16x2 b, float c) {
#if __has_builtin(__builtin_amdgcn_fdot2)
    return __builtin_amdgcn_fdot2(a, b, c, false);
#else
    return fmaf((float)a[0], (float)b[0], fmaf((float)a[1], (float)b[1], c));
#endif
}

// ---------------- K0: MFMA A-frag weight prep, all f16 (BN folded) ----------
__global__ void k0_prep(const float* __restrict__ Wq,
                        const float* __restrict__ Wr, const float* __restrict__ Wf,
                        const float* __restrict__ Wp,
                        const float* __restrict__ brec,
                        const float* __restrict__ bn1g, const float* __restrict__ bn1b,
                        const float* __restrict__ bfus,
                        const float* __restrict__ bn2g, const float* __restrict__ bn2b,
                        short* __restrict__ WqA, short* __restrict__ WrA,
                        short* __restrict__ WfA, short* __restrict__ WpA,
                        float* __restrict__ bias1, float* __restrict__ bias2) {
    const float invs = 1.0f / sqrtf(1.0f + 1e-5f);
    int idx = blockIdx.x * 256 + threadIdx.x;
    if (idx < 12288) {   // WqA: 3 chunks x 2 K-tiles x 4 M-tiles
        int e = idx & 7, l = (idx >> 3) & 63, m = (idx >> 9) & 3;
        int t = (idx >> 11) & 1, c = idx >> 12;
        int out = c*64 + 16*m + (l & 15), k = 32*t + ((l >> 4) << 3) + e;
        WqA[idx] = f2h(Wq[out*64 + k]);
        return;
    }
    int i = idx - 12288;
    if (i < 4096) {      // WrA
        int e = i & 7, l = (i >> 3) & 63, m = (i >> 9) & 3, t = (i >> 11) & 1;
        int out = 16*m + (l & 15), k = 32*t + ((l >> 4) << 3) + e;
        WrA[i] = f2h(Wr[out*64 + k] * bn1g[out] * invs);
        return;
    }
    i -= 4096;
    if (i < 8192) {      // WfA
        int e = i & 7, l = (i >> 3) & 63, m = (i >> 9) & 3, t = (i >> 11) & 3;
        int out = 16*m + (l & 15), k = 32*t + ((l >> 4) << 3) + e;
        WfA[i] = f2h(Wf[out*128 + k] * bn2g[out] * invs);
        return;
    }
    i -= 8192;
    if (i < 4096) {      // WpA
        int e = i & 7, l = (i >> 3) & 63, m = (i >> 9) & 3, t = (i >> 11) & 1;
        int out = 16*m + (l & 15), k = 32*t + ((l >> 4) << 3) + e;
        WpA[i] = f2h(Wp[out*64 + k]);
        return;
    }
    i -= 4096;
    if (i < 64)       bias1[i]    = brec[i]    * bn1g[i]    * invs + bn1b[i];
    else if (i < 128) bias2[i-64] = bfus[i-64] * bn2g[i-64] * invs + bn2b[i-64];
}

// ---------------- K1: pointwise qkv conv via f16 MFMA, f16 output -----------
__global__ __launch_bounds__(256) void k1_qkv(const float* __restrict__ x,
        const short* __restrict__ WqA, const float* __restrict__ bq,
        short* __restrict__ qkv) {
    __shared__ __align__(16) float Xs[64 * 64];
    const int tid = threadIdx.x, lane = tid & 63, wv = tid >> 6;
    const int blk = blockIdx.x;
    const int b = blk >> 10, n0 = (blk & 1023) << 6;
    const float* xg = x + ((long long)b * 64) * NPOS + n0;
    #pragma unroll
    for (int kk = 0; kk < 4; ++kk) {
        int idx = tid + kk * 256;
        int ch = idx >> 4, p = (idx & 15) << 2;
        *(float4*)(Xs + ch * 64 + p) = *(const float4*)(xg + (long long)ch * NPOS + p);
    }
    const int bcol  = wv * 16 + (lane & 15);
    const int bk    = (lane >> 4) << 3;
    const int drow0 = (lane >> 4) << 2;
    __syncthreads();

    h16x8 B0, B1;
    #pragma unroll
    for (int e = 0; e < 8; ++e) B0[e] = (_Float16)Xs[(bk + e) * 64 + bcol];
    #pragma unroll
    for (int e = 0; e < 8; ++e) B1[e] = (_Float16)Xs[(32 + bk + e) * 64 + bcol];

    short* outb = qkv + ((long long)b * 192) * NPOS + n0 + bcol;
    #pragma unroll
    for (int c = 0; c < 3; ++c) {
        #pragma unroll
        for (int m = 0; m < 4; ++m) {
            h16x8 A0 = *(const h16x8*)(WqA + (((c * 2 + 0) * 4 + m) * 64 + lane) * 8);
            h16x8 A1 = *(const h16x8*)(WqA + (((c * 2 + 1) * 4 + m) * 64 + lane) * 8);
            f32x4 a = {0.f, 0.f, 0.f, 0.f};
            a = __builtin_amdgcn_mfma_f32_16x16x32_f16(A0, B0, a, 0, 0, 0);
            a = __builtin_amdgcn_mfma_f32_16x16x32_f16(A1, B1, a, 0, 0, 0);
            float4 bb = *(const float4*)(bq + c * 64 + 16 * m + drow0);
            a[0] += bb.x; a[1] += bb.y; a[2] += bb.z; a[3] += bb.w;
            #pragma unroll
            for (int r = 0; r < 4; ++r)
                outb[(long long)(c * 64 + 16 * m + drow0 + r) * NPOS] = f2h(a[r]);
        }
    }
}

// ---------------- K2: depthwise 3x3x3, f16, wide rows, b128-only reads ------
// Block: 4d x 16h x 64w of one (b,c). Tile: 6 planes x 18 rows x stride 80
// f16 (17.3 KB -> 8 blocks/CU = 32 waves), data at e=8+w, zero side pads.
// Thread = (wg 0..7, oh 0..15, dh 0..1): 8w x 2d outputs. Per tap-row:
// 3 x ds_read_b128 (16 lanes tile 32 banks 2-way = free; L=q0.w, R=q2.x).
__global__ __launch_bounds__(256) void k2_dw(const short* __restrict__ qkv,
        const float* __restrict__ Wd, const float* __restrict__ bd,
        short* __restrict__ qkv2) {
    __shared__ __align__(16) _Float16 tile[108 * 80];
    __shared__ unsigned wpk01[9], wpk2z[9];
    __shared__ float bsh[1];
    const int tid = threadIdx.x;
    const int bc  = blockIdx.x >> 4;        // 0..383 = b*192 + c
    const int sub = blockIdx.x & 15;
    const int d0  = (sub >> 2) << 2;        // 0,4,8,12
    const int h0  = (sub & 3) << 4;         // 0,16,32,48
    const int c   = bc % 192;

    if (tid < 9) {                           // pack weights: (W0,W1),(W2,0)
        const float* wb = Wd + c * 27 + tid * 3;
        f16x2 a = {(_Float16)wb[0], (_Float16)wb[1]};
        f16x2 z = {(_Float16)wb[2], (_Float16)0.f};
        wpk01[tid] = (unsigned)h2i(a);
        wpk2z[tid] = (unsigned)h2i(z);
    }
    if (tid == 31) bsh[0] = bd[c];

    // zero side pads
    for (int r = tid; r < 108; r += 256) {
        *(int4*)(tile + r * 80)      = make_int4(0, 0, 0, 0);   // e[0..8)
        *(int4*)(tile + r * 80 + 72) = make_int4(0, 0, 0, 0);   // e[72..80)
    }
    const short* in = qkv + (long long)bc * NPOS;
    for (int i = tid; i < 864; i += 256) {   // 108 rows x 8 chunks of 8 f16
        const int r = i >> 3, q8 = i & 7;
        const int dd = r / 18;               // 0..5
        const int hh = r - dd * 18;          // 0..17
        const int d = d0 + dd - 1;
        const int h = h0 + hh - 1;
        int4 u = make_int4(0, 0, 0, 0);
        if (d >= 0 && d < DD && h >= 0 && h < HHH)
            u = *(const int4*)(in + (d << 12) + (h << 6) + (q8 << 3));
        *(int4*)(tile + r * 80 + 8 + (q8 << 3)) = u;
    }
    __syncthreads();

    unsigned w01r[9], w2zr[9];
    #pragma unroll
    for (int s = 0; s < 9; ++s) { w01r[s] = wpk01[s]; w2zr[s] = wpk2z[s]; }
    const float bias = bsh[0];

    const int wg = tid & 7;                 // w0 = 8*wg
    const int oh = (tid >> 3) & 15;         // 0..15
    const int o0 = (tid >> 7) << 1;         // d-half: output rows o0, o0+1
    const int w0 = wg << 3;

    float acc[2][8];                        // [odr][j]
    #pragma unroll
    for (int odr = 0; odr < 2; ++odr)
        #pragma unroll
        for (int j = 0; j < 8; ++j) acc[odr][j] = bias;

    #pragma unroll
    for (int kh = 0; kh < 3; ++kh) {
        #pragma unroll
        for (int dp = 0; dp < 4; ++dp) {    // tile plane = o0+dp
            const _Float16* row = tile + ((o0 + dp) * 18 + oh + kh) * 80;
            const int4 q0 = *(const int4*)(row + w0);        // e0..e7 (L=.w)
            const int4 d4 = *(const int4*)(row + w0 + 8);    // e8..e15
            const int4 q2 = *(const int4*)(row + w0 + 16);   // e16..e23 (R=.x)
            int P[10];
            P[0] = __builtin_amdgcn_alignbit(d4.x, q0.w, 16);
            P[1] = d4.x;
            P[2] = __builtin_amdgcn_alignbit(d4.y, d4.x, 16);
            P[3] = d4.y;
            P[4] = __builtin_amdgcn_alignbit(d4.z, d4.y, 16);
            P[5] = d4.z;
            P[6] = __builtin_amdgcn_alignbit(d4.w, d4.z, 16);
            P[7] = d4.w;
            P[8] = __builtin_amdgcn_alignbit(q2.x, d4.w, 16);
            P[9] = q2.x;
            #pragma unroll
            for (int odr = 0; odr < 2; ++odr) {
                const int kd = dp - odr;    // plane feeds od with kd=dp-odr
                if (kd < 0 || kd > 2) continue;
                const f16x2 w01 = i2h((int)w01r[kd * 3 + kh]);
                const f16x2 w2z = i2h((int)w2zr[kd * 3 + kh]);
                #pragma unroll
                for (int j = 0; j < 8; ++j) {
                    acc[odr][j] = fdot2f(w01, i2h(P[j]), acc[odr][j]);
                    acc[odr][j] = fdot2f(w2z, i2h(P[j + 2]), acc[odr][j]);
                }
            }
        }
    }
    short* outp = qkv2 + (long long)bc * NPOS + (h0 + oh) * 64 + w0;
    #pragma unroll
    for (int odr = 0; odr < 2; ++odr) {
        union { s16x4 s4[2]; int4 i4; } o;
        #pragma unroll
        for (int j = 0; j < 8; ++j) o.s4[j >> 2][j & 3] = f2h(acc[odr][j]);
        *(int4*)(outp + ((d0 + o0 + odr) << 12)) = o.i4;
    }
}

// ---------------- K3: Gram via f16 MFMA: G16 = [q;k] @ [q;k]^T --------------
__global__ __launch_bounds__(256) void k3_gram(const short* __restrict__ qkv2,
                                               float* __restrict__ partial) {
    const int blk = blockIdx.x;
    const int chunk = blk & (K3CHUNK - 1);
    const int bh = blk >> 6;                  // 0..15
    const int b = bh >> 3, h = bh & 7;
    const int tid = threadIdx.x, lane = tid & 63, wv = tid >> 6;
    const short* base = qkv2 + ((long long)b * 192 + h * 8) * NPOS;
    const int ch = lane & 15;
    const long long roff = (ch < 8 ? (long long)ch : (long long)(56 + ch)) * NPOS;
    const short* p = base + roff + chunk * 1024 + wv * 256 + ((lane >> 4) << 3);

    f32x4 a0 = {0.f, 0.f, 0.f, 0.f}, a1 = {0.f, 0.f, 0.f, 0.f};
    #pragma unroll
    for (int it = 0; it < 4; ++it) {
        h16x8 f0 = *(const h16x8*)(p + it * 64);
        h16x8 f1 = *(const h16x8*)(p + it * 64 + 32);
        a0 = __builtin_amdgcn_mfma_f32_16x16x32_f16(f0, f0, a0, 0, 0, 0);
        a1 = __builtin_amdgcn_mfma_f32_16x16x32_f16(f1, f1, a1, 0, 0, 0);
    }
    __shared__ float gs[4][256];
    #pragma unroll
    for (int r = 0; r < 4; ++r)
        gs[wv][(((lane >> 4) << 2) + r) * 16 + (lane & 15)] = a0[r] + a1[r];
    __syncthreads();
    const int row = tid >> 4, col = tid & 15;
    float v = gs[0][tid] + gs[1][tid] + gs[2][tid] + gs[3][tid];
    float* pp = partial + ((long long)bh * K3CHUNK + chunk) * 80;
    if (row < 8 && col >= 8)      pp[row * 8 + (col - 8)] = v;   // qk
    else if (row == col && row < 8) pp[64 + row] = v;            // qq
    else if (row == col)            pp[72 + row - 8] = v;        // kk
}

// ---------------- K34: chunk reduce + attn/topk/softmax + P frags (fused) ---
__global__ __launch_bounds__(256) void k34_combine(const float* __restrict__ partial,
        const float* __restrict__ temp, const float* __restrict__ aw,
        short* __restrict__ PA) {
    __shared__ float gram[1280];
    __shared__ float P[1024];
    const int tid = threadIdx.x;
    for (int s = tid; s < 1280; s += 256) {
        int bh = s / 80, slot = s % 80;
        float acc = 0.f;
        for (int c = 0; c < K3CHUNK; ++c)
            acc += partial[((long long)bh * K3CHUNK + c) * 80 + slot];
        gram[s] = acc;
    }
    __syncthreads();
    if (tid < 128) {
        int bh = tid >> 3, i = tid & 7;
        int h = bh & 7;
        const float* g = gram + bh * 80;
        float qn = fmaxf(sqrtf(g[64 + i]), 1e-12f);
        float tp = temp[h];
        float attn[8];
        #pragma unroll
        for (int j = 0; j < 8; ++j) {
            float kn = fmaxf(sqrtf(g[72 + j]), 1e-12f);
            attn[j] = g[i * 8 + j] / (qn * kn) * tp;
        }
        float awv[4];
        float am = -3.4e38f;
        for (int r = 0; r < 4; ++r) { awv[r] = aw[r]; am = fmaxf(am, awv[r]); }
        float asum = 0.f;
        for (int r = 0; r < 4; ++r) { awv[r] = expf(awv[r] - am); asum += awv[r]; }
        const int kvs[4] = {4, 5, 6, 6};   // int(8*ratio) for 0.5,0.67,0.75,0.8
        float Pacc[8];
        #pragma unroll
        for (int j = 0; j < 8; ++j) Pacc[j] = 0.f;
        for (int r = 0; r < 4; ++r) {
            float sw = awv[r] / asum;
            int kv = kvs[r];
            bool sel[8];
            #pragma unroll
            for (int j = 0; j < 8; ++j) sel[j] = false;
            for (int m = 0; m < kv; ++m) { // exact top_k: ties -> smallest index
                int best = 0; float bv = -3.4e38f;
                for (int j = 0; j < 8; ++j)
                    if (!sel[j] && attn[j] > bv) { bv = attn[j]; best = j; }
                sel[best] = true;
            }
            float mx = -3.4e38f;
            for (int j = 0; j < 8; ++j) if (sel[j]) mx = fmaxf(mx, attn[j]);
            float es = 0.f, e[8];
            for (int j = 0; j < 8; ++j) { e[j] = sel[j] ? expf(attn[j] - mx) : 0.f; es += e[j]; }
            for (int j = 0; j < 8; ++j) Pacc[j] += sw * e[j] / es;
        }
        for (int j = 0; j < 8; ++j) P[tid * 8 + j] = Pacc[j];
    }
    __syncthreads();
    for (int idx = tid; idx < 8192; idx += 256) {  // PA: 2b x 2t x 4m x 64l x 8e
        int e = idx & 7, l = (idx >> 3) & 63, m = (idx >> 9) & 3;
        int t = (idx >> 11) & 1, b = idx >> 12;
        int out = 16*m + (l & 15), k = 32*t + ((l >> 4) << 3) + e;
        float v = ((k >> 3) == (out >> 3)) ? P[(b * 64 + out) * 8 + (k & 7)] : 0.f;
        PA[idx] = f2h(v);
    }
}

// ---------------- K5: fused tail via f16 MFMA, barrier-free stages ----------
__global__ __launch_bounds__(256) void k5_tail(
        const short* __restrict__ qkv2, const float* __restrict__ x,
        const short* __restrict__ PA, const short* __restrict__ WrA,
        const short* __restrict__ WfA, const short* __restrict__ WpA,
        const float* __restrict__ bias1, const float* __restrict__ bias2,
        const float* __restrict__ bp, float* __restrict__ out) {
    __shared__ __align__(16) float As[64 * 64];
    __shared__ __align__(16) float Xs[64 * 64];
    const int tid = threadIdx.x, lane = tid & 63, wv = tid >> 6;
    const int blk = blockIdx.x;
    const int b = blk >> 10, n0 = (blk & 1023) << 6;
    const short* vg = qkv2 + ((long long)b * 192 + 128) * NPOS + n0;
    const float* xg = x + ((long long)b * 64) * NPOS + n0;
    #pragma unroll
    for (int kk = 0; kk < 4; ++kk) {
        int idx = tid + kk * 256;            // [64ch][64pos] float4 tiles
        int ch = idx >> 4, p = (idx & 15) << 2;
        *(float4*)(Xs + ch * 64 + p) = *(const float4*)(xg + (long long)ch * NPOS + p);
    }
    #pragma unroll
    for (int kk = 0; kk < 2; ++kk) {         // v: 512 chunks of 8 f16
        int i = tid + kk * 256;
        int ch = i >> 3, p0 = (i & 7) << 3;
        h16x8 raw = *(const h16x8*)(vg + (long long)ch * NPOS + p0);
        *(float4*)(As + ch * 64 + p0) =
            make_float4((float)raw[0], (float)raw[1], (float)raw[2], (float)raw[3]);
        *(float4*)(As + ch * 64 + p0 + 4) =
            make_float4((float)raw[4], (float)raw[5], (float)raw[6], (float)raw[7]);
    }
    h16x8 pA[2][4];
    #pragma unroll
    for (int t = 0; t < 2; ++t)
        #pragma unroll
        for (int m = 0; m < 4; ++m)
            pA[t][m] = *(const h16x8*)(PA + (((b * 2 + t) * 4 + m) * 64 + lane) * 8);
    const int bcol  = wv * 16 + (lane & 15);   // B col / D col (wave-private)
    const int bk    = (lane >> 4) << 3;        // B/A k-slice base
    const int drow0 = (lane >> 4) << 2;        // D row base within 16-tile
    __syncthreads();                            // the ONLY block-wide barrier

    auto loadB = [&](const float* S, int kbase) {
        h16x8 r;
        #pragma unroll
        for (int e = 0; e < 8; ++e) r[e] = (_Float16)S[(kbase + bk + e) * 64 + bcol];
        return r;
    };

    // ---- stage1: weighted = P_blockdiag @ v
    f32x4 Dw[4];
    {
        h16x8 B0 = loadB(As, 0), B1 = loadB(As, 32);
        #pragma unroll
        for (int m = 0; m < 4; ++m) {
            f32x4 a = {0.f, 0.f, 0.f, 0.f};
            a = __builtin_amdgcn_mfma_f32_16x16x32_f16(pA[0][m], B0, a, 0, 0, 0);
            a = __builtin_amdgcn_mfma_f32_16x16x32_f16(pA[1][m], B1, a, 0, 0, 0);
            Dw[m] = a;
        }
    }
    #pragma unroll
    for (int m = 0; m < 4; ++m)
        #pragma unroll
        for (int r = 0; r < 4; ++r)
            As[(16 * m + drow0 + r) * 64 + bcol] = Dw[m][r];

    // ---- stage2: rec = sigmoid(Wr'@weighted + bias1); enh = weighted*rec
    float enh[4][4];
    {
        h16x8 rA[2][4];
        #pragma unroll
        for (int t = 0; t < 2; ++t)
            #pragma unroll
            for (int m = 0; m < 4; ++m)
                rA[t][m] = *(const h16x8*)(WrA + ((t * 4 + m) * 64 + lane) * 8);
        h16x8 B0 = loadB(As, 0), B1 = loadB(As, 32);
        #pragma unroll
        for (int m = 0; m < 4; ++m) {
            f32x4 a = {0.f, 0.f, 0.f, 0.f};
            a = __builtin_amdgcn_mfma_f32_16x16x32_f16(rA[0][m], B0, a, 0, 0, 0);
            a = __builtin_amdgcn_mfma_f32_16x16x32_f16(rA[1][m], B1, a, 0, 0, 0);
            #pragma unroll
            for (int r = 0; r < 4; ++r) {
                float z = a[r] + bias1[16 * m + drow0 + r];
                enh[m][r] = Dw[m][r] / (1.f + expf(-z));
            }
        }
    }
    #pragma unroll
    for (int m = 0; m < 4; ++m)
        #pragma unroll
        for (int r = 0; r < 4; ++r)
            As[(16 * m + drow0 + r) * 64 + bcol] = enh[m][r];

    // ---- stage3: fusz = Wf'@[enh; x] + bias2
    f32x4 D3[4];
    {
        h16x8 fA[4][4];
        #pragma unroll
        for (int t = 0; t < 4; ++t)
            #pragma unroll
            for (int m = 0; m < 4; ++m)
                fA[t][m] = *(const h16x8*)(WfA + ((t * 4 + m) * 64 + lane) * 8);
        h16x8 B0 = loadB(As, 0), B1 = loadB(As, 32);
        h16x8 B2 = loadB(Xs, 0), B3 = loadB(Xs, 32);
        #pragma unroll
        for (int m = 0; m < 4; ++m) {
            f32x4 a = {0.f, 0.f, 0.f, 0.f};
            a = __builtin_amdgcn_mfma_f32_16x16x32_f16(fA[0][m], B0, a, 0, 0, 0);
            a = __builtin_amdgcn_mfma_f32_16x16x32_f16(fA[1][m], B1, a, 0, 0, 0);
            a = __builtin_amdgcn_mfma_f32_16x16x32_f16(fA[2][m], B2, a, 0, 0, 0);
            a = __builtin_amdgcn_mfma_f32_16x16x32_f16(fA[3][m], B3, a, 0, 0, 0);
            #pragma unroll
            for (int r = 0; r < 4; ++r) a[r] += bias2[16 * m + drow0 + r];
            D3[m] = a;
        }
    }
    #pragma unroll
    for (int m = 0; m < 4; ++m)
        #pragma unroll
        for (int r = 0; r < 4; ++r)
            As[(16 * m + drow0 + r) * 64 + bcol] = D3[m][r];

    // ---- stage4: out = Wp@fusz + bp, direct global store
    {
        h16x8 qA[2][4];
        #pragma unroll
        for (int t = 0; t < 2; ++t)
            #pragma unroll
            for (int m = 0; m < 4; ++m)
                qA[t][m] = *(const h16x8*)(WpA + ((t * 4 + m) * 64 + lane) * 8);
        h16x8 B0 = loadB(As, 0), B1 = loadB(As, 32);
        float* outb = out + ((long long)b * 64) * NPOS + n0 + bcol;
        #pragma unroll
        for (int m = 0; m < 4; ++m) {
            f32x4 a = {0.f, 0.f, 0.f, 0.f};
            a = __builtin_amdgcn_mfma_f32_16x16x32_f16(qA[0][m], B0, a, 0, 0, 0);
            a = __builtin_amdgcn_mfma_f32_16x16x32_f16(qA[1][m], B1, a, 0, 0, 0);
            #pragma unroll
            for (int r = 0; r < 4; ++r)
                outb[(long long)(16 * m + drow0 + r) * NPOS] =
                    a[r] + bp[16 * m + drow0 + r];
        }
    }
}

extern "C" void kernel_launch(void* const* d_in, const int* in_sizes, int n_in,
                              void* d_out, int out_size, void* d_ws, size_t ws_size,
                              hipStream_t stream) {
    (void)in_sizes; (void)n_in; (void)out_size; (void)ws_size;
    const float* x     = (const float*)d_in[0];
    const float* w_qkv = (const float*)d_in[1];
    const float* b_qkv = (const float*)d_in[2];
    const float* w_dw  = (const float*)d_in[3];
    const float* b_dw  = (const float*)d_in[4];
    const float* temp  = (const float*)d_in[5];
    const float* aw    = (const float*)d_in[6];
    const float* w_rec = (const float*)d_in[7];
    const float* b_rec = (const float*)d_in[8];
    const float* bn1g  = (const float*)d_in[9];
    const float* bn1b  = (const float*)d_in[10];
    const float* w_fus = (const float*)d_in[11];
    const float* b_fus = (const float*)d_in[12];
    const float* bn2g  = (const float*)d_in[13];
    const float* bn2b  = (const float*)d_in[14];
    const float* w_prj = (const float*)d_in[15];
    const float* b_prj = (const float*)d_in[16];
    float* out = (float*)d_out;

    short* qkv  = (short*)d_ws;             // 25165824 f16 (50.3 MB)
    short* qkv2 = qkv + 25165824;           // 25165824 f16
    float* part = (float*)(qkv2 + 25165824);// 16*64*80 = 81920 f32
    float* bias1 = part + 81920;            // 64
    float* bias2 = bias1 + 64;              // 64
    short* WqA  = (short*)(bias2 + 64);     // 12288 shorts
    short* WrA  = WqA + 12288;              // 4096 shorts
    short* WfA  = WrA + 4096;               // 8192 shorts
    short* WpA  = WfA + 8192;               // 4096 shorts
    short* PAb  = WpA + 4096;               // 8192 shorts

    k0_prep<<<113, 256, 0, stream>>>(w_qkv, w_rec, w_fus, w_prj, b_rec, bn1g, bn1b,
                                     b_fus, bn2g, bn2b, WqA, WrA, WfA, WpA, bias1, bias2);
    k1_qkv<<<2048, 256, 0, stream>>>(x, WqA, b_qkv, qkv);
    k2_dw<<<6144, 256, 0, stream>>>(qkv, w_dw, b_dw, qkv2);
    k3_gram<<<16 * K3CHUNK, 256, 0, stream>>>(qkv2, part);
    k34_combine<<<1, 256, 0, stream>>>(part, temp, aw, PAb);
    k5_tail<<<2048, 256, 0, stream>>>(qkv2, x, PAb, WrA, WfA, WpA,
                                      bias1, bias2, b_prj, out);
}

// Round 18
// 109.924 us; speedup vs baseline: 1.0960x; 1.0960x over previous
//
#include <hip/hip_runtime.h>
#include <math.h>

#define NPOS 65536          // D*H*W = 16*64*64
#define DD 16
#define HHH 64
#define WWW 64
#define K3CHUNK 64

typedef __attribute__((ext_vector_type(8))) _Float16 h16x8;  // 8 f16 (4 VGPR)
typedef __attribute__((ext_vector_type(4))) short s16x4;
typedef __attribute__((ext_vector_type(4))) float f32x4;
typedef __attribute__((ext_vector_type(2))) _Float16 f16x2;

static __device__ __forceinline__ short f2h(float f) {
    union { _Float16 h; short s; } v; v.h = (_Float16)f; return v.s;
}
static __device__ __forceinline__ f16x2 i2h(int i) {
    union { int i; f16x2 h; } v; v.i = i; return v.h;
}
static __device__ __forceinline__ int h2i(f16x2 h) {
    union { int i; f16x2 h; } v; v.h = h; return v.i;
}
static __device__ __forceinline__ float fdot2f(f16x2 a, f16x2 b, float c) {
#if __has_builtin(__builtin_amdgcn_fdot2)
    return __builtin_amdgcn_fdot2(a, b, c, false);
#else
    return fmaf((float)a[0], (float)b[0], fmaf((float)a[1], (float)b[1], c));
#endif
}

// ---------------- K0: MFMA A-frag weight prep, all f16 (BN folded) ----------
__global__ void k0_prep(const float* __restrict__ Wq,
                        const float* __restrict__ Wr, const float* __restrict__ Wf,
                        const float* __restrict__ Wp,
                        const float* __restrict__ brec,
                        const float* __restrict__ bn1g, const float* __restrict__ bn1b,
                        const float* __restrict__ bfus,
                        const float* __restrict__ bn2g, const float* __restrict__ bn2b,
                        short* __restrict__ WqA, short* __restrict__ WrA,
                        short* __restrict__ WfA, short* __restrict__ WpA,
                        float* __restrict__ bias1, float* __restrict__ bias2) {
    const float invs = 1.0f / sqrtf(1.0f + 1e-5f);
    int idx = blockIdx.x * 256 + threadIdx.x;
    if (idx < 12288) {   // WqA: 3 chunks x 2 K-tiles x 4 M-tiles
        int e = idx & 7, l = (idx >> 3) & 63, m = (idx >> 9) & 3;
        int t = (idx >> 11) & 1, c = idx >> 12;
        int out = c*64 + 16*m + (l & 15), k = 32*t + ((l >> 4) << 3) + e;
        WqA[idx] = f2h(Wq[out*64 + k]);
        return;
    }
    int i = idx - 12288;
    if (i < 4096) {      // WrA
        int e = i & 7, l = (i >> 3) & 63, m = (i >> 9) & 3, t = (i >> 11) & 1;
        int out = 16*m + (l & 15), k = 32*t + ((l >> 4) << 3) + e;
        WrA[i] = f2h(Wr[out*64 + k] * bn1g[out] * invs);
        return;
    }
    i -= 4096;
    if (i < 8192) {      // WfA
        int e = i & 7, l = (i >> 3) & 63, m = (i >> 9) & 3, t = (i >> 11) & 3;
        int out = 16*m + (l & 15), k = 32*t + ((l >> 4) << 3) + e;
        WfA[i] = f2h(Wf[out*128 + k] * bn2g[out] * invs);
        return;
    }
    i -= 8192;
    if (i < 4096) {      // WpA
        int e = i & 7, l = (i >> 3) & 63, m = (i >> 9) & 3, t = (i >> 11) & 1;
        int out = 16*m + (l & 15), k = 32*t + ((l >> 4) << 3) + e;
        WpA[i] = f2h(Wp[out*64 + k]);
        return;
    }
    i -= 4096;
    if (i < 64)       bias1[i]    = brec[i]    * bn1g[i]    * invs + bn1b[i];
    else if (i < 128) bias2[i-64] = bfus[i-64] * bn2g[i-64] * invs + bn2b[i-64];
}

// ---------------- K1: pointwise qkv conv via f16 MFMA, f16 output -----------
__global__ __launch_bounds__(256) void k1_qkv(const float* __restrict__ x,
        const short* __restrict__ WqA, const float* __restrict__ bq,
        short* __restrict__ qkv) {
    __shared__ __align__(16) float Xs[64 * 64];
    const int tid = threadIdx.x, lane = tid & 63, wv = tid >> 6;
    const int blk = blockIdx.x;
    const int b = blk >> 10, n0 = (blk & 1023) << 6;
    const float* xg = x + ((long long)b * 64) * NPOS + n0;
    #pragma unroll
    for (int kk = 0; kk < 4; ++kk) {
        int idx = tid + kk * 256;
        int ch = idx >> 4, p = (idx & 15) << 2;
        *(float4*)(Xs + ch * 64 + p) = *(const float4*)(xg + (long long)ch * NPOS + p);
    }
    const int bcol  = wv * 16 + (lane & 15);
    const int bk    = (lane >> 4) << 3;
    const int drow0 = (lane >> 4) << 2;
    __syncthreads();

    h16x8 B0, B1;
    #pragma unroll
    for (int e = 0; e < 8; ++e) B0[e] = (_Float16)Xs[(bk + e) * 64 + bcol];
    #pragma unroll
    for (int e = 0; e < 8; ++e) B1[e] = (_Float16)Xs[(32 + bk + e) * 64 + bcol];

    short* outb = qkv + ((long long)b * 192) * NPOS + n0 + bcol;
    #pragma unroll
    for (int c = 0; c < 3; ++c) {
        #pragma unroll
        for (int m = 0; m < 4; ++m) {
            h16x8 A0 = *(const h16x8*)(WqA + (((c * 2 + 0) * 4 + m) * 64 + lane) * 8);
            h16x8 A1 = *(const h16x8*)(WqA + (((c * 2 + 1) * 4 + m) * 64 + lane) * 8);
            f32x4 a = {0.f, 0.f, 0.f, 0.f};
            a = __builtin_amdgcn_mfma_f32_16x16x32_f16(A0, B0, a, 0, 0, 0);
            a = __builtin_amdgcn_mfma_f32_16x16x32_f16(A1, B1, a, 0, 0, 0);
            float4 bb = *(const float4*)(bq + c * 64 + 16 * m + drow0);
            a[0] += bb.x; a[1] += bb.y; a[2] += bb.z; a[3] += bb.w;
            #pragma unroll
            for (int r = 0; r < 4; ++r)
                outb[(long long)(c * 64 + 16 * m + drow0 + r) * NPOS] = f2h(a[r]);
        }
    }
}

// ---------------- K2: depthwise 3x3x3 conv, f16 in/out, raw-copy staging ----
// (round-15 variant: best measured) Tile f16 [108][72] (15.6 KB, 8 blk/CU).
// Per tap-row: one b64 (2 dwords = win1..win4), 2 dword-shuffles for edges,
// 3 alignbit -> 5 packed pairs; per (row,od): 8 dot2 (fp32 accum).
__global__ __launch_bounds__(256) void k2_dw(const short* __restrict__ qkv,
        const float* __restrict__ Wd, const float* __restrict__ bd,
        short* __restrict__ qkv2) {
    __shared__ __align__(16) _Float16 tile[108 * 72];
    __shared__ unsigned wpk01[9], wpk2z[9];
    __shared__ float bsh[1];
    const int tid = threadIdx.x;
    const int lane = tid & 63;
    const int bc  = blockIdx.x >> 4;        // 0..383 = b*192 + c
    const int sub = blockIdx.x & 15;
    const int d0  = (sub >> 2) << 2;        // 0,4,8,12
    const int h0  = (sub & 3) << 4;         // 0,16,32,48
    const int c   = bc % 192;

    if (tid < 9) {                           // pack weights: (W0,W1),(W2,0)
        const float* wb = Wd + c * 27 + tid * 3;
        f16x2 a = {(_Float16)wb[0], (_Float16)wb[1]};
        f16x2 z = {(_Float16)wb[2], (_Float16)0.f};
        wpk01[tid] = (unsigned)h2i(a);
        wpk2z[tid] = (unsigned)h2i(z);
    }
    if (tid == 31) bsh[0] = bd[c];

    const short* in = qkv + (long long)bc * NPOS;
    for (int i = tid; i < 864; i += 256) {   // 108 rows x 8 chunks of 8 f16
        const int r = i >> 3, q8 = i & 7;
        const int dd = r / 18;               // 0..5
        const int hh = r - dd * 18;          // 0..17
        const int d = d0 + dd - 1;
        const int h = h0 + hh - 1;
        int4 u = make_int4(0, 0, 0, 0);
        if (d >= 0 && d < DD && h >= 0 && h < HHH)
            u = *(const int4*)(in + (d << 12) + (h << 6) + (q8 << 3));
        *(int4*)(tile + r * 72 + (q8 << 3)) = u;
    }
    __syncthreads();

    unsigned w01r[9], w2zr[9];
    #pragma unroll
    for (int s = 0; s < 9; ++s) { w01r[s] = wpk01[s]; w2zr[s] = wpk2z[s]; }
    const float bias = bsh[0];

    const int wl = tid & 15;                // w-group: w0 = 4*wl
    const int oh = tid >> 4;                // 0..15
    const int w0 = wl << 2;

    float acc[4][4];                        // [od][j]
    #pragma unroll
    for (int od = 0; od < 4; ++od)
        #pragma unroll
        for (int j = 0; j < 4; ++j) acc[od][j] = bias;

    #pragma unroll
    for (int kh = 0; kh < 3; ++kh) {
        #pragma unroll
        for (int dp = 0; dp < 6; ++dp) {    // tile d-plane (abs d = d0+dp-1)
            const int2 dd2 = *(const int2*)(tile + (dp * 18 + oh + kh) * 72 + w0);
            int Ldw = __shfl(dd2.y, (lane + 63) & 63, 64);
            int Rdw = __shfl(dd2.x, (lane + 1) & 63, 64);
            Ldw = (wl == 0)  ? 0 : Ldw;     // w=-1 zero pad
            Rdw = (wl == 15) ? 0 : Rdw;     // w=64 zero pad
            int pr[5];
            pr[0] = __builtin_amdgcn_alignbit(dd2.x, Ldw, 16);  // (win0,win1)
            pr[1] = dd2.x;                                       // (win1,win2)
            pr[2] = __builtin_amdgcn_alignbit(dd2.y, dd2.x, 16); // (win2,win3)
            pr[3] = dd2.y;                                       // (win3,win4)
            pr[4] = __builtin_amdgcn_alignbit(Rdw, dd2.y, 16);   // (win4,win5)
            #pragma unroll
            for (int od = 0; od < 4; ++od) {
                const int kd = dp - od;     // plane dp feeds od with kd=dp-od
                if (kd < 0 || kd > 2) continue;
                const f16x2 w01 = i2h((int)w01r[kd * 3 + kh]);
                const f16x2 w2z = i2h((int)w2zr[kd * 3 + kh]);
                #pragma unroll
                for (int j = 0; j < 4; ++j) {
                    acc[od][j] = fdot2f(w01, i2h(pr[j]), acc[od][j]);
                    acc[od][j] = fdot2f(w2z, i2h(pr[j + 2]), acc[od][j]);
                }
            }
        }
    }
    short* outp = qkv2 + (long long)bc * NPOS + (h0 + oh) * 64 + w0;
    #pragma unroll
    for (int od = 0; od < 4; ++od) {
        s16x4 o;
        #pragma unroll
        for (int j = 0; j < 4; ++j) o[j] = f2h(acc[od][j]);
        *(s16x4*)(outp + ((d0 + od) << 12)) = o;
    }
}

// ---------------- K3: Gram via f16 MFMA: G16 = [q;k] @ [q;k]^T --------------
__global__ __launch_bounds__(256) void k3_gram(const short* __restrict__ qkv2,
                                               float* __restrict__ partial) {
    const int blk = blockIdx.x;
    const int chunk = blk & (K3CHUNK - 1);
    const int bh = blk >> 6;                  // 0..15
    const int b = bh >> 3, h = bh & 7;
    const int tid = threadIdx.x, lane = tid & 63, wv = tid >> 6;
    const short* base = qkv2 + ((long long)b * 192 + h * 8) * NPOS;
    const int ch = lane & 15;
    const long long roff = (ch < 8 ? (long long)ch : (long long)(56 + ch)) * NPOS;
    const short* p = base + roff + chunk * 1024 + wv * 256 + ((lane >> 4) << 3);

    f32x4 a0 = {0.f, 0.f, 0.f, 0.f}, a1 = {0.f, 0.f, 0.f, 0.f};
    #pragma unroll
    for (int it = 0; it < 4; ++it) {
        h16x8 f0 = *(const h16x8*)(p + it * 64);
        h16x8 f1 = *(const h16x8*)(p + it * 64 + 32);
        a0 = __builtin_amdgcn_mfma_f32_16x16x32_f16(f0, f0, a0, 0, 0, 0);
        a1 = __builtin_amdgcn_mfma_f32_16x16x32_f16(f1, f1, a1, 0, 0, 0);
    }
    __shared__ float gs[4][256];
    #pragma unroll
    for (int r = 0; r < 4; ++r)
        gs[wv][(((lane >> 4) << 2) + r) * 16 + (lane & 15)] = a0[r] + a1[r];
    __syncthreads();
    const int row = tid >> 4, col = tid & 15;
    float v = gs[0][tid] + gs[1][tid] + gs[2][tid] + gs[3][tid];
    float* pp = partial + ((long long)bh * K3CHUNK + chunk) * 80;
    if (row < 8 && col >= 8)      pp[row * 8 + (col - 8)] = v;   // qk
    else if (row == col && row < 8) pp[64 + row] = v;            // qq
    else if (row == col)            pp[72 + row - 8] = v;        // kk
}

// ---------------- K34: chunk reduce + attn/topk/softmax + P frags (fused) ---
__global__ __launch_bounds__(256) void k34_combine(const float* __restrict__ partial,
        const float* __restrict__ temp, const float* __restrict__ aw,
        short* __restrict__ PA) {
    __shared__ float gram[1280];
    __shared__ float P[1024];
    const int tid = threadIdx.x;
    for (int s = tid; s < 1280; s += 256) {
        int bh = s / 80, slot = s % 80;
        float acc = 0.f;
        for (int c = 0; c < K3CHUNK; ++c)
            acc += partial[((long long)bh * K3CHUNK + c) * 80 + slot];
        gram[s] = acc;
    }
    __syncthreads();
    if (tid < 128) {
        int bh = tid >> 3, i = tid & 7;
        int h = bh & 7;
        const float* g = gram + bh * 80;
        float qn = fmaxf(sqrtf(g[64 + i]), 1e-12f);
        float tp = temp[h];
        float attn[8];
        #pragma unroll
        for (int j = 0; j < 8; ++j) {
            float kn = fmaxf(sqrtf(g[72 + j]), 1e-12f);
            attn[j] = g[i * 8 + j] / (qn * kn) * tp;
        }
        float awv[4];
        float am = -3.4e38f;
        for (int r = 0; r < 4; ++r) { awv[r] = aw[r]; am = fmaxf(am, awv[r]); }
        float asum = 0.f;
        for (int r = 0; r < 4; ++r) { awv[r] = expf(awv[r] - am); asum += awv[r]; }
        const int kvs[4] = {4, 5, 6, 6};   // int(8*ratio) for 0.5,0.67,0.75,0.8
        float Pacc[8];
        #pragma unroll
        for (int j = 0; j < 8; ++j) Pacc[j] = 0.f;
        for (int r = 0; r < 4; ++r) {
            float sw = awv[r] / asum;
            int kv = kvs[r];
            bool sel[8];
            #pragma unroll
            for (int j = 0; j < 8; ++j) sel[j] = false;
            for (int m = 0; m < kv; ++m) { // exact top_k: ties -> smallest index
                int best = 0; float bv = -3.4e38f;
                for (int j = 0; j < 8; ++j)
                    if (!sel[j] && attn[j] > bv) { bv = attn[j]; best = j; }
                sel[best] = true;
            }
            float mx = -3.4e38f;
            for (int j = 0; j < 8; ++j) if (sel[j]) mx = fmaxf(mx, attn[j]);
            float es = 0.f, e[8];
            for (int j = 0; j < 8; ++j) { e[j] = sel[j] ? expf(attn[j] - mx) : 0.f; es += e[j]; }
            for (int j = 0; j < 8; ++j) Pacc[j] += sw * e[j] / es;
        }
        for (int j = 0; j < 8; ++j) P[tid * 8 + j] = Pacc[j];
    }
    __syncthreads();
    for (int idx = tid; idx < 8192; idx += 256) {  // PA: 2b x 2t x 4m x 64l x 8e
        int e = idx & 7, l = (idx >> 3) & 63, m = (idx >> 9) & 3;
        int t = (idx >> 11) & 1, b = idx >> 12;
        int out = 16*m + (l & 15), k = 32*t + ((l >> 4) << 3) + e;
        float v = ((k >> 3) == (out >> 3)) ? P[(b * 64 + out) * 8 + (k & 7)] : 0.f;
        PA[idx] = f2h(v);
    }
}

// ---------------- K5: fused tail via f16 MFMA, barrier-free stages ----------
__global__ __launch_bounds__(256) void k5_tail(
        const short* __restrict__ qkv2, const float* __restrict__ x,
        const short* __restrict__ PA, const short* __restrict__ WrA,
        const short* __restrict__ WfA, const short* __restrict__ WpA,
        const float* __restrict__ bias1, const float* __restrict__ bias2,
        const float* __restrict__ bp, float* __restrict__ out) {
    __shared__ __align__(16) float As[64 * 64];
    __shared__ __align__(16) float Xs[64 * 64];
    const int tid = threadIdx.x, lane = tid & 63, wv = tid >> 6;
    const int blk = blockIdx.x;
    const int b = blk >> 10, n0 = (blk & 1023) << 6;
    const short* vg = qkv2 + ((long long)b * 192 + 128) * NPOS + n0;
    const float* xg = x + ((long long)b * 64) * NPOS + n0;
    #pragma unroll
    for (int kk = 0; kk < 4; ++kk) {
        int idx = tid + kk * 256;            // [64ch][64pos] float4 tiles
        int ch = idx >> 4, p = (idx & 15) << 2;
        *(float4*)(Xs + ch * 64 + p) = *(const float4*)(xg + (long long)ch * NPOS + p);
    }
    #pragma unroll
    for (int kk = 0; kk < 2; ++kk) {         // v: 512 chunks of 8 f16
        int i = tid + kk * 256;
        int ch = i >> 3, p0 = (i & 7) << 3;
        h16x8 raw = *(const h16x8*)(vg + (long long)ch * NPOS + p0);
        *(float4*)(As + ch * 64 + p0) =
            make_float4((float)raw[0], (float)raw[1], (float)raw[2], (float)raw[3]);
        *(float4*)(As + ch * 64 + p0 + 4) =
            make_float4((float)raw[4], (float)raw[5], (float)raw[6], (float)raw[7]);
    }
    h16x8 pA[2][4];
    #pragma unroll
    for (int t = 0; t < 2; ++t)
        #pragma unroll
        for (int m = 0; m < 4; ++m)
            pA[t][m] = *(const h16x8*)(PA + (((b * 2 + t) * 4 + m) * 64 + lane) * 8);
    const int bcol  = wv * 16 + (lane & 15);   // B col / D col (wave-private)
    const int bk    = (lane >> 4) << 3;        // B/A k-slice base
    const int drow0 = (lane >> 4) << 2;        // D row base within 16-tile
    __syncthreads();                            // the ONLY block-wide barrier

    auto loadB = [&](const float* S, int kbase) {
        h16x8 r;
        #pragma unroll
        for (int e = 0; e < 8; ++e) r[e] = (_Float16)S[(kbase + bk + e) * 64 + bcol];
        return r;
    };

    // ---- stage1: weighted = P_blockdiag @ v
    f32x4 Dw[4];
    {
        h16x8 B0 = loadB(As, 0), B1 = loadB(As, 32);
        #pragma unroll
        for (int m = 0; m < 4; ++m) {
            f32x4 a = {0.f, 0.f, 0.f, 0.f};
            a = __builtin_amdgcn_mfma_f32_16x16x32_f16(pA[0][m], B0, a, 0, 0, 0);
            a = __builtin_amdgcn_mfma_f32_16x16x32_f16(pA[1][m], B1, a, 0, 0, 0);
            Dw[m] = a;
        }
    }
    #pragma unroll
    for (int m = 0; m < 4; ++m)
        #pragma unroll
        for (int r = 0; r < 4; ++r)
            As[(16 * m + drow0 + r) * 64 + bcol] = Dw[m][r];

    // ---- stage2: rec = sigmoid(Wr'@weighted + bias1); enh = weighted*rec
    float enh[4][4];
    {
        h16x8 rA[2][4];
        #pragma unroll
        for (int t = 0; t < 2; ++t)
            #pragma unroll
            for (int m = 0; m < 4; ++m)
                rA[t][m] = *(const h16x8*)(WrA + ((t * 4 + m) * 64 + lane) * 8);
        h16x8 B0 = loadB(As, 0), B1 = loadB(As, 32);
        #pragma unroll
        for (int m = 0; m < 4; ++m) {
            f32x4 a = {0.f, 0.f, 0.f, 0.f};
            a = __builtin_amdgcn_mfma_f32_16x16x32_f16(rA[0][m], B0, a, 0, 0, 0);
            a = __builtin_amdgcn_mfma_f32_16x16x32_f16(rA[1][m], B1, a, 0, 0, 0);
            #pragma unroll
            for (int r = 0; r < 4; ++r) {
                float z = a[r] + bias1[16 * m + drow0 + r];
                enh[m][r] = Dw[m][r] / (1.f + expf(-z));
            }
        }
    }
    #pragma unroll
    for (int m = 0; m < 4; ++m)
        #pragma unroll
        for (int r = 0; r < 4; ++r)
            As[(16 * m + drow0 + r) * 64 + bcol] = enh[m][r];

    // ---- stage3: fusz = Wf'@[enh; x] + bias2
    f32x4 D3[4];
    {
        h16x8 fA[4][4];
        #pragma unroll
        for (int t = 0; t < 4; ++t)
            #pragma unroll
            for (int m = 0; m < 4; ++m)
                fA[t][m] = *(const h16x8*)(WfA + ((t * 4 + m) * 64 + lane) * 8);
        h16x8 B0 = loadB(As, 0), B1 = loadB(As, 32);
        h16x8 B2 = loadB(Xs, 0), B3 = loadB(Xs, 32);
        #pragma unroll
        for (int m = 0; m < 4; ++m) {
            f32x4 a = {0.f, 0.f, 0.f, 0.f};
            a = __builtin_amdgcn_mfma_f32_16x16x32_f16(fA[0][m], B0, a, 0, 0, 0);
            a = __builtin_amdgcn_mfma_f32_16x16x32_f16(fA[1][m], B1, a, 0, 0, 0);
            a = __builtin_amdgcn_mfma_f32_16x16x32_f16(fA[2][m], B2, a, 0, 0, 0);
            a = __builtin_amdgcn_mfma_f32_16x16x32_f16(fA[3][m], B3, a, 0, 0, 0);
            #pragma unroll
            for (int r = 0; r < 4; ++r) a[r] += bias2[16 * m + drow0 + r];
            D3[m] = a;
        }
    }
    #pragma unroll
    for (int m = 0; m < 4; ++m)
        #pragma unroll
        for (int r = 0; r < 4; ++r)
            As[(16 * m + drow0 + r) * 64 + bcol] = D3[m][r];

    // ---- stage4: out = Wp@fusz + bp, direct global store
    {
        h16x8 qA[2][4];
        #pragma unroll
        for (int t = 0; t < 2; ++t)
            #pragma unroll
            for (int m = 0; m < 4; ++m)
                qA[t][m] = *(const h16x8*)(WpA + ((t * 4 + m) * 64 + lane) * 8);
        h16x8 B0 = loadB(As, 0), B1 = loadB(As, 32);
        float* outb = out + ((long long)b * 64) * NPOS + n0 + bcol;
        #pragma unroll
        for (int m = 0; m < 4; ++m) {
            f32x4 a = {0.f, 0.f, 0.f, 0.f};
            a = __builtin_amdgcn_mfma_f32_16x16x32_f16(qA[0][m], B0, a, 0, 0, 0);
            a = __builtin_amdgcn_mfma_f32_16x16x32_f16(qA[1][m], B1, a, 0, 0, 0);
            #pragma unroll
            for (int r = 0; r < 4; ++r)
                outb[(long long)(16 * m + drow0 + r) * NPOS] =
                    a[r] + bp[16 * m + drow0 + r];
        }
    }
}

extern "C" void kernel_launch(void* const* d_in, const int* in_sizes, int n_in,
                              void* d_out, int out_size, void* d_ws, size_t ws_size,
                              hipStream_t stream) {
    (void)in_sizes; (void)n_in; (void)out_size; (void)ws_size;
    const float* x     = (const float*)d_in[0];
    const float* w_qkv = (const float*)d_in[1];
    const float* b_qkv = (const float*)d_in[2];
    const float* w_dw  = (const float*)d_in[3];
    const float* b_dw  = (const float*)d_in[4];
    const float* temp  = (const float*)d_in[5];
    const float* aw    = (const float*)d_in[6];
    const float* w_rec = (const float*)d_in[7];
    const float* b_rec = (const float*)d_in[8];
    const float* bn1g  = (const float*)d_in[9];
    const float* bn1b  = (const float*)d_in[10];
    const float* w_fus = (const float*)d_in[11];
    const float* b_fus = (const float*)d_in[12];
    const float* bn2g  = (const float*)d_in[13];
    const float* bn2b  = (const float*)d_in[14];
    const float* w_prj = (const float*)d_in[15];
    const float* b_prj = (const float*)d_in[16];
    float* out = (float*)d_out;

    short* qkv  = (short*)d_ws;             // 25165824 f16 (50.3 MB)
    short* qkv2 = qkv + 25165824;           // 25165824 f16
    float* part = (float*)(qkv2 + 25165824);// 16*64*80 = 81920 f32
    float* bias1 = part + 81920;            // 64
    float* bias2 = bias1 + 64;              // 64
    short* WqA  = (short*)(bias2 + 64);     // 12288 shorts
    short* WrA  = WqA + 12288;              // 4096 shorts
    short* WfA  = WrA + 4096;               // 8192 shorts
    short* WpA  = WfA + 8192;               // 4096 shorts
    short* PAb  = WpA + 4096;               // 8192 shorts

    k0_prep<<<113, 256, 0, stream>>>(w_qkv, w_rec, w_fus, w_prj, b_rec, bn1g, bn1b,
                                     b_fus, bn2g, bn2b, WqA, WrA, WfA, WpA, bias1, bias2);
    k1_qkv<<<2048, 256, 0, stream>>>(x, WqA, b_qkv, qkv);
    k2_dw<<<6144, 256, 0, stream>>>(qkv, w_dw, b_dw, qkv2);
    k3_gram<<<16 * K3CHUNK, 256, 0, stream>>>(qkv2, part);
    k34_combine<<<1, 256, 0, stream>>>(part, temp, aw, PAb);
    k5_tail<<<2048, 256, 0, stream>>>(qkv2, x, PAb, WrA, WfA, WpA,
                                      bias1, bias2, b_prj, out);
}

// Round 19
// 108.097 us; speedup vs baseline: 1.1145x; 1.0169x over previous
//
#include <hip/hip_runtime.h>
#include <math.h>

#define NPOS 65536          // D*H*W = 16*64*64
#define DD 16
#define HHH 64
#define WWW 64
#define K3CHUNK 64

typedef __attribute__((ext_vector_type(8))) _Float16 h16x8;  // 8 f16 (4 VGPR)
typedef __attribute__((ext_vector_type(4))) short s16x4;
typedef __attribute__((ext_vector_type(4))) float f32x4;
typedef __attribute__((ext_vector_type(2))) _Float16 f16x2;

static __device__ __forceinline__ short f2h(float f) {
    union { _Float16 h; short s; } v; v.h = (_Float16)f; return v.s;
}
static __device__ __forceinline__ f16x2 i2h(int i) {
    union { int i; f16x2 h; } v; v.i = i; return v.h;
}
static __device__ __forceinline__ int h2i(f16x2 h) {
    union { int i; f16x2 h; } v; v.h = h; return v.i;
}
static __device__ __forceinline__ float fdot2f(f16x2 a, f16x2 b, float c) {
#if __has_builtin(__builtin_amdgcn_fdot2)
    return __builtin_amdgcn_fdot2(a, b, c, false);
#else
    return fmaf((float)a[0], (float)b[0], fmaf((float)a[1], (float)b[1], c));
#endif
}

// ---------------- K0: MFMA A-frag weight prep, all f16 (BN folded) ----------
__global__ void k0_prep(const float* __restrict__ Wq,
                        const float* __restrict__ Wr, const float* __restrict__ Wf,
                        const float* __restrict__ Wp,
                        const float* __restrict__ brec,
                        const float* __restrict__ bn1g, const float* __restrict__ bn1b,
                        const float* __restrict__ bfus,
                        const float* __restrict__ bn2g, const float* __restrict__ bn2b,
                        short* __restrict__ WqA, short* __restrict__ WrA,
                        short* __restrict__ WfA, short* __restrict__ WpA,
                        float* __restrict__ bias1, float* __restrict__ bias2,
                        float* __restrict__ zbuf) {
    const float invs = 1.0f / sqrtf(1.0f + 1e-5f);
    int idx = blockIdx.x * 256 + threadIdx.x;
    if (idx < 12288) {   // WqA: 3 chunks x 2 K-tiles x 4 M-tiles
        int e = idx & 7, l = (idx >> 3) & 63, m = (idx >> 9) & 3;
        int t = (idx >> 11) & 1, c = idx >> 12;
        int out = c*64 + 16*m + (l & 15), k = 32*t + ((l >> 4) << 3) + e;
        WqA[idx] = f2h(Wq[out*64 + k]);
        return;
    }
    int i = idx - 12288;
    if (i < 4096) {      // WrA
        int e = i & 7, l = (i >> 3) & 63, m = (i >> 9) & 3, t = (i >> 11) & 1;
        int out = 16*m + (l & 15), k = 32*t + ((l >> 4) << 3) + e;
        WrA[i] = f2h(Wr[out*64 + k] * bn1g[out] * invs);
        return;
    }
    i -= 4096;
    if (i < 8192) {      // WfA
        int e = i & 7, l = (i >> 3) & 63, m = (i >> 9) & 3, t = (i >> 11) & 3;
        int out = 16*m + (l & 15), k = 32*t + ((l >> 4) << 3) + e;
        WfA[i] = f2h(Wf[out*128 + k] * bn2g[out] * invs);
        return;
    }
    i -= 8192;
    if (i < 4096) {      // WpA
        int e = i & 7, l = (i >> 3) & 63, m = (i >> 9) & 3, t = (i >> 11) & 1;
        int out = 16*m + (l & 15), k = 32*t + ((l >> 4) << 3) + e;
        WpA[i] = f2h(Wp[out*64 + k]);
        return;
    }
    i -= 4096;
    if (i < 64)       bias1[i]    = brec[i]    * bn1g[i]    * invs + bn1b[i];
    else if (i < 128) bias2[i-64] = bfus[i-64] * bn2g[i-64] * invs + bn2b[i-64];
    else if (i < 144) zbuf[i-128] = 0.f;     // zero source for OOB halo rows
}

// ---------------- K1: pointwise qkv conv via f16 MFMA, f16 output -----------
__global__ __launch_bounds__(256) void k1_qkv(const float* __restrict__ x,
        const short* __restrict__ WqA, const float* __restrict__ bq,
        short* __restrict__ qkv) {
    __shared__ __align__(16) float Xs[64 * 64];
    const int tid = threadIdx.x, lane = tid & 63, wv = tid >> 6;
    const int blk = blockIdx.x;
    const int b = blk >> 10, n0 = (blk & 1023) << 6;
    const float* xg = x + ((long long)b * 64) * NPOS + n0;
    #pragma unroll
    for (int kk = 0; kk < 4; ++kk) {
        int idx = tid + kk * 256;
        int ch = idx >> 4, p = (idx & 15) << 2;
        *(float4*)(Xs + ch * 64 + p) = *(const float4*)(xg + (long long)ch * NPOS + p);
    }
    const int bcol  = wv * 16 + (lane & 15);
    const int bk    = (lane >> 4) << 3;
    const int drow0 = (lane >> 4) << 2;
    __syncthreads();

    h16x8 B0, B1;
    #pragma unroll
    for (int e = 0; e < 8; ++e) B0[e] = (_Float16)Xs[(bk + e) * 64 + bcol];
    #pragma unroll
    for (int e = 0; e < 8; ++e) B1[e] = (_Float16)Xs[(32 + bk + e) * 64 + bcol];

    short* outb = qkv + ((long long)b * 192) * NPOS + n0 + bcol;
    #pragma unroll
    for (int c = 0; c < 3; ++c) {
        #pragma unroll
        for (int m = 0; m < 4; ++m) {
            h16x8 A0 = *(const h16x8*)(WqA + (((c * 2 + 0) * 4 + m) * 64 + lane) * 8);
            h16x8 A1 = *(const h16x8*)(WqA + (((c * 2 + 1) * 4 + m) * 64 + lane) * 8);
            f32x4 a = {0.f, 0.f, 0.f, 0.f};
            a = __builtin_amdgcn_mfma_f32_16x16x32_f16(A0, B0, a, 0, 0, 0);
            a = __builtin_amdgcn_mfma_f32_16x16x32_f16(A1, B1, a, 0, 0, 0);
            float4 bb = *(const float4*)(bq + c * 64 + 16 * m + drow0);
            a[0] += bb.x; a[1] += bb.y; a[2] += bb.z; a[3] += bb.w;
            #pragma unroll
            for (int r = 0; r < 4; ++r)
                outb[(long long)(c * 64 + 16 * m + drow0 + r) * NPOS] = f2h(a[r]);
        }
    }
}

// ---------------- K2: depthwise 3x3x3 conv, f16, async LDS staging ----------
// Tile f16 [108][64] = 13.8 KB, fully contiguous -> staged via
// global_load_lds (lds dest = base + lane*16, the HW pattern); OOB halo rows
// source from a zeroed 64B scratch. Compute: per tap-row one b64 + 2 lane
// shuffles + 3 alignbit -> 5 packed pairs; 8 dot2 per (row,od), fp32 accum.
__global__ __launch_bounds__(256) void k2_dw(const short* __restrict__ qkv,
        const float* __restrict__ Wd, const float* __restrict__ bd,
        const short* __restrict__ zsrc, short* __restrict__ qkv2) {
    __shared__ __align__(16) _Float16 tile[108 * 64];
    __shared__ unsigned wpk01[9], wpk2z[9];
    __shared__ float bsh[1];
    const int tid = threadIdx.x;
    const int lane = tid & 63;
    const int bc  = blockIdx.x >> 4;        // 0..383 = b*192 + c
    const int sub = blockIdx.x & 15;
    const int d0  = (sub >> 2) << 2;        // 0,4,8,12
    const int h0  = (sub & 3) << 4;         // 0,16,32,48
    const int c   = bc % 192;

    if (tid < 9) {                           // pack weights: (W0,W1),(W2,0)
        const float* wb = Wd + c * 27 + tid * 3;
        f16x2 a = {(_Float16)wb[0], (_Float16)wb[1]};
        f16x2 z = {(_Float16)wb[2], (_Float16)0.f};
        wpk01[tid] = (unsigned)h2i(a);
        wpk2z[tid] = (unsigned)h2i(z);
    }
    if (tid == 31) bsh[0] = bd[c];

    const short* in = qkv + (long long)bc * NPOS;
#if __has_builtin(__builtin_amdgcn_global_load_lds)
    for (int i = tid; i < 864; i += 256) {   // 864 chunks of 16B, contiguous
        const int r = i >> 3, q8 = i & 7;
        const int dd = r / 18;               // 0..5
        const int hh = r - dd * 18;          // 0..17
        const int d = d0 + dd - 1;
        const int h = h0 + hh - 1;
        const short* src = (d >= 0 && d < DD && h >= 0 && h < HHH)
            ? in + (d << 12) + (h << 6) + (q8 << 3) : zsrc;
        __builtin_amdgcn_global_load_lds(
            (const __attribute__((address_space(1))) unsigned*)(const void*)src,
            (__attribute__((address_space(3))) unsigned*)(void*)(tile + i * 8),
            16, 0, 0);
    }
#else
    for (int i = tid; i < 864; i += 256) {
        const int r = i >> 3, q8 = i & 7;
        const int dd = r / 18;
        const int hh = r - dd * 18;
        const int d = d0 + dd - 1;
        const int h = h0 + hh - 1;
        int4 u = make_int4(0, 0, 0, 0);
        if (d >= 0 && d < DD && h >= 0 && h < HHH)
            u = *(const int4*)(in + (d << 12) + (h << 6) + (q8 << 3));
        *(int4*)(tile + i * 8) = u;
    }
    (void)zsrc;
#endif
    __syncthreads();

    unsigned w01r[9], w2zr[9];
    #pragma unroll
    for (int s = 0; s < 9; ++s) { w01r[s] = wpk01[s]; w2zr[s] = wpk2z[s]; }
    const float bias = bsh[0];

    const int wl = tid & 15;                // w-group: w0 = 4*wl
    const int oh = tid >> 4;                // 0..15
    const int w0 = wl << 2;

    float acc[4][4];                        // [od][j]
    #pragma unroll
    for (int od = 0; od < 4; ++od)
        #pragma unroll
        for (int j = 0; j < 4; ++j) acc[od][j] = bias;

    #pragma unroll
    for (int kh = 0; kh < 3; ++kh) {
        #pragma unroll
        for (int dp = 0; dp < 6; ++dp) {    // tile d-plane (abs d = d0+dp-1)
            const int2 dd2 = *(const int2*)(tile + (dp * 18 + oh + kh) * 64 + w0);
            int Ldw = __shfl(dd2.y, (lane + 63) & 63, 64);
            int Rdw = __shfl(dd2.x, (lane + 1) & 63, 64);
            Ldw = (wl == 0)  ? 0 : Ldw;     // w=-1 zero pad
            Rdw = (wl == 15) ? 0 : Rdw;     // w=64 zero pad
            int pr[5];
            pr[0] = __builtin_amdgcn_alignbit(dd2.x, Ldw, 16);  // (win0,win1)
            pr[1] = dd2.x;                                       // (win1,win2)
            pr[2] = __builtin_amdgcn_alignbit(dd2.y, dd2.x, 16); // (win2,win3)
            pr[3] = dd2.y;                                       // (win3,win4)
            pr[4] = __builtin_amdgcn_alignbit(Rdw, dd2.y, 16);   // (win4,win5)
            #pragma unroll
            for (int od = 0; od < 4; ++od) {
                const int kd = dp - od;     // plane dp feeds od with kd=dp-od
                if (kd < 0 || kd > 2) continue;
                const f16x2 w01 = i2h((int)w01r[kd * 3 + kh]);
                const f16x2 w2z = i2h((int)w2zr[kd * 3 + kh]);
                #pragma unroll
                for (int j = 0; j < 4; ++j) {
                    acc[od][j] = fdot2f(w01, i2h(pr[j]), acc[od][j]);
                    acc[od][j] = fdot2f(w2z, i2h(pr[j + 2]), acc[od][j]);
                }
            }
        }
    }
    short* outp = qkv2 + (long long)bc * NPOS + (h0 + oh) * 64 + w0;
    #pragma unroll
    for (int od = 0; od < 4; ++od) {
        s16x4 o;
        #pragma unroll
        for (int j = 0; j < 4; ++j) o[j] = f2h(acc[od][j]);
        *(s16x4*)(outp + ((d0 + od) << 12)) = o;
    }
}

// ---------------- K3: Gram via f16 MFMA: G16 = [q;k] @ [q;k]^T --------------
__global__ __launch_bounds__(256) void k3_gram(const short* __restrict__ qkv2,
                                               float* __restrict__ partial) {
    const int blk = blockIdx.x;
    const int chunk = blk & (K3CHUNK - 1);
    const int bh = blk >> 6;                  // 0..15
    const int b = bh >> 3, h = bh & 7;
    const int tid = threadIdx.x, lane = tid & 63, wv = tid >> 6;
    const short* base = qkv2 + ((long long)b * 192 + h * 8) * NPOS;
    const int ch = lane & 15;
    const long long roff = (ch < 8 ? (long long)ch : (long long)(56 + ch)) * NPOS;
    const short* p = base + roff + chunk * 1024 + wv * 256 + ((lane >> 4) << 3);

    f32x4 a0 = {0.f, 0.f, 0.f, 0.f}, a1 = {0.f, 0.f, 0.f, 0.f};
    #pragma unroll
    for (int it = 0; it < 4; ++it) {
        h16x8 f0 = *(const h16x8*)(p + it * 64);
        h16x8 f1 = *(const h16x8*)(p + it * 64 + 32);
        a0 = __builtin_amdgcn_mfma_f32_16x16x32_f16(f0, f0, a0, 0, 0, 0);
        a1 = __builtin_amdgcn_mfma_f32_16x16x32_f16(f1, f1, a1, 0, 0, 0);
    }
    __shared__ float gs[4][256];
    #pragma unroll
    for (int r = 0; r < 4; ++r)
        gs[wv][(((lane >> 4) << 2) + r) * 16 + (lane & 15)] = a0[r] + a1[r];
    __syncthreads();
    const int row = tid >> 4, col = tid & 15;
    float v = gs[0][tid] + gs[1][tid] + gs[2][tid] + gs[3][tid];
    float* pp = partial + ((long long)bh * K3CHUNK + chunk) * 80;
    if (row < 8 && col >= 8)      pp[row * 8 + (col - 8)] = v;   // qk
    else if (row == col && row < 8) pp[64 + row] = v;            // qq
    else if (row == col)            pp[72 + row - 8] = v;        // kk
}

// ---------------- K34: chunk reduce + attn/topk/softmax + P frags (fused) ---
__global__ __launch_bounds__(256) void k34_combine(const float* __restrict__ partial,
        const float* __restrict__ temp, const float* __restrict__ aw,
        short* __restrict__ PA) {
    __shared__ float gram[1280];
    __shared__ float P[1024];
    const int tid = threadIdx.x;
    for (int s = tid; s < 1280; s += 256) {
        int bh = s / 80, slot = s % 80;
        float acc = 0.f;
        for (int c = 0; c < K3CHUNK; ++c)
            acc += partial[((long long)bh * K3CHUNK + c) * 80 + slot];
        gram[s] = acc;
    }
    __syncthreads();
    if (tid < 128) {
        int bh = tid >> 3, i = tid & 7;
        int h = bh & 7;
        const float* g = gram + bh * 80;
        float qn = fmaxf(sqrtf(g[64 + i]), 1e-12f);
        float tp = temp[h];
        float attn[8];
        #pragma unroll
        for (int j = 0; j < 8; ++j) {
            float kn = fmaxf(sqrtf(g[72 + j]), 1e-12f);
            attn[j] = g[i * 8 + j] / (qn * kn) * tp;
        }
        float awv[4];
        float am = -3.4e38f;
        for (int r = 0; r < 4; ++r) { awv[r] = aw[r]; am = fmaxf(am, awv[r]); }
        float asum = 0.f;
        for (int r = 0; r < 4; ++r) { awv[r] = expf(awv[r] - am); asum += awv[r]; }
        const int kvs[4] = {4, 5, 6, 6};   // int(8*ratio) for 0.5,0.67,0.75,0.8
        float Pacc[8];
        #pragma unroll
        for (int j = 0; j < 8; ++j) Pacc[j] = 0.f;
        for (int r = 0; r < 4; ++r) {
            float sw = awv[r] / asum;
            int kv = kvs[r];
            bool sel[8];
            #pragma unroll
            for (int j = 0; j < 8; ++j) sel[j] = false;
            for (int m = 0; m < kv; ++m) { // exact top_k: ties -> smallest index
                int best = 0; float bv = -3.4e38f;
                for (int j = 0; j < 8; ++j)
                    if (!sel[j] && attn[j] > bv) { bv = attn[j]; best = j; }
                sel[best] = true;
            }
            float mx = -3.4e38f;
            for (int j = 0; j < 8; ++j) if (sel[j]) mx = fmaxf(mx, attn[j]);
            float es = 0.f, e[8];
            for (int j = 0; j < 8; ++j) { e[j] = sel[j] ? expf(attn[j] - mx) : 0.f; es += e[j]; }
            for (int j = 0; j < 8; ++j) Pacc[j] += sw * e[j] / es;
        }
        for (int j = 0; j < 8; ++j) P[tid * 8 + j] = Pacc[j];
    }
    __syncthreads();
    for (int idx = tid; idx < 8192; idx += 256) {  // PA: 2b x 2t x 4m x 64l x 8e
        int e = idx & 7, l = (idx >> 3) & 63, m = (idx >> 9) & 3;
        int t = (idx >> 11) & 1, b = idx >> 12;
        int out = 16*m + (l & 15), k = 32*t + ((l >> 4) << 3) + e;
        float v = ((k >> 3) == (out >> 3)) ? P[(b * 64 + out) * 8 + (k & 7)] : 0.f;
        PA[idx] = f2h(v);
    }
}

// ---------------- K5: fused tail via f16 MFMA, barrier-free stages ----------
__global__ __launch_bounds__(256) void k5_tail(
        const short* __restrict__ qkv2, const float* __restrict__ x,
        const short* __restrict__ PA, const short* __restrict__ WrA,
        const short* __restrict__ WfA, const short* __restrict__ WpA,
        const float* __restrict__ bias1, const float* __restrict__ bias2,
        const float* __restrict__ bp, float* __restrict__ out) {
    __shared__ __align__(16) float As[64 * 64];
    __shared__ __align__(16) float Xs[64 * 64];
    const int tid = threadIdx.x, lane = tid & 63, wv = tid >> 6;
    const int blk = blockIdx.x;
    const int b = blk >> 10, n0 = (blk & 1023) << 6;
    const short* vg = qkv2 + ((long long)b * 192 + 128) * NPOS + n0;
    const float* xg = x + ((long long)b * 64) * NPOS + n0;
    #pragma unroll
    for (int kk = 0; kk < 4; ++kk) {
        int idx = tid + kk * 256;            // [64ch][64pos] float4 tiles
        int ch = idx >> 4, p = (idx & 15) << 2;
        *(float4*)(Xs + ch * 64 + p) = *(const float4*)(xg + (long long)ch * NPOS + p);
    }
    #pragma unroll
    for (int kk = 0; kk < 2; ++kk) {         // v: 512 chunks of 8 f16
        int i = tid + kk * 256;
        int ch = i >> 3, p0 = (i & 7) << 3;
        h16x8 raw = *(const h16x8*)(vg + (long long)ch * NPOS + p0);
        *(float4*)(As + ch * 64 + p0) =
            make_float4((float)raw[0], (float)raw[1], (float)raw[2], (float)raw[3]);
        *(float4*)(As + ch * 64 + p0 + 4) =
            make_float4((float)raw[4], (float)raw[5], (float)raw[6], (float)raw[7]);
    }
    h16x8 pA[2][4];
    #pragma unroll
    for (int t = 0; t < 2; ++t)
        #pragma unroll
        for (int m = 0; m < 4; ++m)
            pA[t][m] = *(const h16x8*)(PA + (((b * 2 + t) * 4 + m) * 64 + lane) * 8);
    const int bcol  = wv * 16 + (lane & 15);   // B col / D col (wave-private)
    const int bk    = (lane >> 4) << 3;        // B/A k-slice base
    const int drow0 = (lane >> 4) << 2;        // D row base within 16-tile
    __syncthreads();                            // the ONLY block-wide barrier

    auto loadB = [&](const float* S, int kbase) {
        h16x8 r;
        #pragma unroll
        for (int e = 0; e < 8; ++e) r[e] = (_Float16)S[(kbase + bk + e) * 64 + bcol];
        return r;
    };

    // ---- stage1: weighted = P_blockdiag @ v
    f32x4 Dw[4];
    {
        h16x8 B0 = loadB(As, 0), B1 = loadB(As, 32);
        #pragma unroll
        for (int m = 0; m < 4; ++m) {
            f32x4 a = {0.f, 0.f, 0.f, 0.f};
            a = __builtin_amdgcn_mfma_f32_16x16x32_f16(pA[0][m], B0, a, 0, 0, 0);
            a = __builtin_amdgcn_mfma_f32_16x16x32_f16(pA[1][m], B1, a, 0, 0, 0);
            Dw[m] = a;
        }
    }
    #pragma unroll
    for (int m = 0; m < 4; ++m)
        #pragma unroll
        for (int r = 0; r < 4; ++r)
            As[(16 * m + drow0 + r) * 64 + bcol] = Dw[m][r];

    // ---- stage2: rec = sigmoid(Wr'@weighted + bias1); enh = weighted*rec
    float enh[4][4];
    {
        h16x8 rA[2][4];
        #pragma unroll
        for (int t = 0; t < 2; ++t)
            #pragma unroll
            for (int m = 0; m < 4; ++m)
                rA[t][m] = *(const h16x8*)(WrA + ((t * 4 + m) * 64 + lane) * 8);
        h16x8 B0 = loadB(As, 0), B1 = loadB(As, 32);
        #pragma unroll
        for (int m = 0; m < 4; ++m) {
            f32x4 a = {0.f, 0.f, 0.f, 0.f};
            a = __builtin_amdgcn_mfma_f32_16x16x32_f16(rA[0][m], B0, a, 0, 0, 0);
            a = __builtin_amdgcn_mfma_f32_16x16x32_f16(rA[1][m], B1, a, 0, 0, 0);
            #pragma unroll
            for (int r = 0; r < 4; ++r) {
                float z = a[r] + bias1[16 * m + drow0 + r];
                enh[m][r] = Dw[m][r] / (1.f + expf(-z));
            }
        }
    }
    #pragma unroll
    for (int m = 0; m < 4; ++m)
        #pragma unroll
        for (int r = 0; r < 4; ++r)
            As[(16 * m + drow0 + r) * 64 + bcol] = enh[m][r];

    // ---- stage3: fusz = Wf'@[enh; x] + bias2
    f32x4 D3[4];
    {
        h16x8 fA[4][4];
        #pragma unroll
        for (int t = 0; t < 4; ++t)
            #pragma unroll
            for (int m = 0; m < 4; ++m)
                fA[t][m] = *(const h16x8*)(WfA + ((t * 4 + m) * 64 + lane) * 8);
        h16x8 B0 = loadB(As, 0), B1 = loadB(As, 32);
        h16x8 B2 = loadB(Xs, 0), B3 = loadB(Xs, 32);
        #pragma unroll
        for (int m = 0; m < 4; ++m) {
            f32x4 a = {0.f, 0.f, 0.f, 0.f};
            a = __builtin_amdgcn_mfma_f32_16x16x32_f16(fA[0][m], B0, a, 0, 0, 0);
            a = __builtin_amdgcn_mfma_f32_16x16x32_f16(fA[1][m], B1, a, 0, 0, 0);
            a = __builtin_amdgcn_mfma_f32_16x16x32_f16(fA[2][m], B2, a, 0, 0, 0);
            a = __builtin_amdgcn_mfma_f32_16x16x32_f16(fA[3][m], B3, a, 0, 0, 0);
            #pragma unroll
            for (int r = 0; r < 4; ++r) a[r] += bias2[16 * m + drow0 + r];
            D3[m] = a;
        }
    }
    #pragma unroll
    for (int m = 0; m < 4; ++m)
        #pragma unroll
        for (int r = 0; r < 4; ++r)
            As[(16 * m + drow0 + r) * 64 + bcol] = D3[m][r];

    // ---- stage4: out = Wp@fusz + bp, direct global store
    {
        h16x8 qA[2][4];
        #pragma unroll
        for (int t = 0; t < 2; ++t)
            #pragma unroll
            for (int m = 0; m < 4; ++m)
                qA[t][m] = *(const h16x8*)(WpA + ((t * 4 + m) * 64 + lane) * 8);
        h16x8 B0 = loadB(As, 0), B1 = loadB(As, 32);
        float* outb = out + ((long long)b * 64) * NPOS + n0 + bcol;
        #pragma unroll
        for (int m = 0; m < 4; ++m) {
            f32x4 a = {0.f, 0.f, 0.f, 0.f};
            a = __builtin_amdgcn_mfma_f32_16x16x32_f16(qA[0][m], B0, a, 0, 0, 0);
            a = __builtin_amdgcn_mfma_f32_16x16x32_f16(qA[1][m], B1, a, 0, 0, 0);
            #pragma unroll
            for (int r = 0; r < 4; ++r)
                outb[(long long)(16 * m + drow0 + r) * NPOS] =
                    a[r] + bp[16 * m + drow0 + r];
        }
    }
}

extern "C" void kernel_launch(void* const* d_in, const int* in_sizes, int n_in,
                              void* d_out, int out_size, void* d_ws, size_t ws_size,
                              hipStream_t stream) {
    (void)in_sizes; (void)n_in; (void)out_size; (void)ws_size;
    const float* x     = (const float*)d_in[0];
    const float* w_qkv = (const float*)d_in[1];
    const float* b_qkv = (const float*)d_in[2];
    const float* w_dw  = (const float*)d_in[3];
    const float* b_dw  = (const float*)d_in[4];
    const float* temp  = (const float*)d_in[5];
    const float* aw    = (const float*)d_in[6];
    const float* w_rec = (const float*)d_in[7];
    const float* b_rec = (const float*)d_in[8];
    const float* bn1g  = (const float*)d_in[9];
    const float* bn1b  = (const float*)d_in[10];
    const float* w_fus = (const float*)d_in[11];
    const float* b_fus = (const float*)d_in[12];
    const float* bn2g  = (const float*)d_in[13];
    const float* bn2b  = (const float*)d_in[14];
    const float* w_prj = (const float*)d_in[15];
    const float* b_prj = (const float*)d_in[16];
    float* out = (float*)d_out;

    short* qkv  = (short*)d_ws;             // 25165824 f16 (50.3 MB)
    short* qkv2 = qkv + 25165824;           // 25165824 f16
    float* part = (float*)(qkv2 + 25165824);// 16*64*80 = 81920 f32
    float* bias1 = part + 81920;            // 64
    float* bias2 = bias1 + 64;              // 64
    short* WqA  = (short*)(bias2 + 64);     // 12288 shorts
    short* WrA  = WqA + 12288;              // 4096 shorts
    short* WfA  = WrA + 4096;               // 8192 shorts
    short* WpA  = WfA + 8192;               // 4096 shorts
    short* PAb  = WpA + 4096;               // 8192 shorts
    float* zbuf = (float*)(PAb + 8192);     // 16 f32 zero scratch (64B)

    k0_prep<<<113, 256, 0, stream>>>(w_qkv, w_rec, w_fus, w_prj, b_rec, bn1g, bn1b,
                                     b_fus, bn2g, bn2b, WqA, WrA, WfA, WpA,
                                     bias1, bias2, zbuf);
    k1_qkv<<<2048, 256, 0, stream>>>(x, WqA, b_qkv, qkv);
    k2_dw<<<6144, 256, 0, stream>>>(qkv, w_dw, b_dw, (const short*)zbuf, qkv2);
    k3_gram<<<16 * K3CHUNK, 256, 0, stream>>>(qkv2, part);
    k34_combine<<<1, 256, 0, stream>>>(part, temp, aw, PAb);
    k5_tail<<<2048, 256, 0, stream>>>(qkv2, x, PAb, WrA, WfA, WpA,
                                      bias1, bias2, b_prj, out);
}